// Round 10
// baseline (298.676 us; speedup 1.0000x reference)
//
#include <hip/hip_runtime.h>

// ChamferLoss: prediction [B,N,3] f32, target [B,M,3] f32 -> scalar f32.
// v10: EXACT pruned NN. R4-R9 established the brute-force kernel sits at the
// fp32 VALU FLOP ceiling (~89 TF; pk_fma is half-rate per element on CDNA4,
// so all instruction variants converge to ~48 us). The only lever left is
// algorithmic: z-slab bucketing (64 buckets) + outward ring scan with exact
// slab-distance lower-bound early exit. Worst case = brute force (correct).
// Pipeline: minmax -> hist -> scan -> scatter -> nn -> sum (6 kernels).

#define NPTS  8192
#define NB    4
#define NBUK  64
#define NSETS 8          // set s: tensor s>>2 (0=pred,1=targ), batch s&3
#define CAP   768        // LDS staging capacity (float4) >= max bucket count

typedef float v4f __attribute__((ext_vector_type(4)));

// ---------- K1: per-set z min/max (+ global acc/counter init) ----------
__global__ __launch_bounds__(1024) void k_minmax(
    const float* __restrict__ pred, const float* __restrict__ targ,
    float* __restrict__ minmaxz, double* __restrict__ acc,
    unsigned int* __restrict__ counter) {
    const int s = blockIdx.x, t = threadIdx.x;
    if (s == 0 && t == 0) { *acc = 0.0; *counter = 0u; }
    const float* P = ((s >> 2) ? targ : pred) + (size_t)(s & 3) * NPTS * 3;
    float lo = 3e38f, hi = -3e38f;
    for (int i = t; i < NPTS; i += 1024) {
        float z = P[3 * i + 2];
        lo = fminf(lo, z); hi = fmaxf(hi, z);
    }
    for (int off = 32; off > 0; off >>= 1) {
        lo = fminf(lo, __shfl_down(lo, off));
        hi = fmaxf(hi, __shfl_down(hi, off));
    }
    __shared__ float slo[16], shi[16];
    const int lane = t & 63, w = t >> 6;
    if (lane == 0) { slo[w] = lo; shi[w] = hi; }
    __syncthreads();
    if (t == 0) {
        for (int i = 1; i < 16; ++i) { lo = fminf(lo, slo[i]); hi = fmaxf(hi, shi[i]); }
        minmaxz[2 * s] = lo;
        minmaxz[2 * s + 1] = hi;
    }
}

// ---------- K2: per-set bucket histogram ----------
__global__ __launch_bounds__(1024) void k_hist(
    const float* __restrict__ pred, const float* __restrict__ targ,
    const float* __restrict__ minmaxz, int* __restrict__ counts) {
    const int s = blockIdx.x, t = threadIdx.x;
    __shared__ int h[NBUK];
    if (t < NBUK) h[t] = 0;
    __syncthreads();
    const float* P = ((s >> 2) ? targ : pred) + (size_t)(s & 3) * NPTS * 3;
    const float zmin = minmaxz[2 * s];
    const float inv = (float)NBUK / fmaxf(minmaxz[2 * s + 1] - zmin, 1e-30f);
    for (int i = t; i < NPTS; i += 1024) {
        int k = (int)((P[3 * i + 2] - zmin) * inv);
        k = min(max(k, 0), NBUK - 1);
        atomicAdd(&h[k], 1);
    }
    __syncthreads();
    if (t < NBUK) counts[s * NBUK + t] = h[t];   // one block per set: plain store
}

// ---------- K3: per-set exclusive scan (1 wave per set, NBUK==64) ----------
__global__ __launch_bounds__(512) void k_scan(
    const int* __restrict__ counts, int* __restrict__ bukoff,
    int* __restrict__ cursor) {
    const int s = threadIdx.x >> 6, lane = threadIdx.x & 63;
    const int v = counts[s * NBUK + lane];
    int inc = v;
    for (int off = 1; off < 64; off <<= 1) {
        int n = __shfl_up(inc, off);
        if (lane >= off) inc += n;
    }
    bukoff[s * (NBUK + 1) + lane + 1] = inc;
    cursor[s * NBUK + lane] = inc - v;          // exclusive prefix
    if (lane == 0) bukoff[s * (NBUK + 1)] = 0;
}

// ---------- K4: scatter points into bucket-sorted float4 arrays ----------
__global__ __launch_bounds__(1024) void k_scatter(
    const float* __restrict__ pred, const float* __restrict__ targ,
    const float* __restrict__ minmaxz, int* __restrict__ cursor,
    v4f* __restrict__ scat) {
    const int s = blockIdx.x, t = threadIdx.x;
    const float* P = ((s >> 2) ? targ : pred) + (size_t)(s & 3) * NPTS * 3;
    const float zmin = minmaxz[2 * s];
    const float inv = (float)NBUK / fmaxf(minmaxz[2 * s + 1] - zmin, 1e-30f);
    for (int i = t; i < NPTS; i += 1024) {
        float x = P[3 * i], y = P[3 * i + 1], z = P[3 * i + 2];
        int k = min(max((int)((z - zmin) * inv), 0), NBUK - 1);
        int pos = atomicAdd(&cursor[s * NBUK + k], 1);
        scat[(size_t)s * NPTS + pos] = (v4f){x, y, z, 0.f};
    }
}

// ---------- K5: ring-pruned exact NN ----------
// Block: 256 threads, 128 consecutive scattered queries (z-coherent).
// Thread t handles query (t&127); halves (t>>7) split candidates (stride 2).
// Ring over Y buckets from the query's slab outward; per-lane exact bound
// (slab-edge z distance), block-uniform expansion via __syncthreads_count.
__global__ __launch_bounds__(256) void k_nn(
    const v4f* __restrict__ scat, const int* __restrict__ bukoff,
    const float* __restrict__ minmaxz, float* __restrict__ bestd) {
    const int chunk = blockIdx.x, b = blockIdx.y, dir = blockIdx.z;
    const int qset = dir ? (4 + b) : b;
    const int yset = dir ? b : (4 + b);
    const v4f* Q = scat + (size_t)qset * NPTS;
    const v4f* Y = scat + (size_t)yset * NPTS;
    const int* off = bukoff + yset * (NBUK + 1);
    const float zminY = minmaxz[2 * yset];
    const float wY = fmaxf(minmaxz[2 * yset + 1] - zminY, 1e-30f) / NBUK;
    const float invY = 1.0f / wY;

    const int t = threadIdx.x;
    const int qi = chunk * 128 + (t & 127);
    const int half = t >> 7;
    const v4f q = Q[qi];
    const float qx = q.x, qy = q.y, qz = q.z;
    float best = 3e38f;

    __shared__ v4f buf[CAP];
    __shared__ int ks_sh;
    if (t == 0) ks_sh = min(max((int)((qz - zminY) * invY), 0), NBUK - 1);
    __syncthreads();
    const int kstart = ks_sh;

    auto scan_bucket = [&](int k) {
        const int s0 = off[k], s1 = off[k + 1];
        for (int base = s0; base < s1; base += CAP) {
            const int n = min(CAP, s1 - base);
            __syncthreads();                         // protect buf reuse
            for (int j = t; j < n; j += 256) buf[j] = Y[base + j];
            __syncthreads();
            for (int j = half; j < n; j += 2) {      // broadcast LDS reads
                v4f c = buf[j];
                float dx = qx - c.x, dy = qy - c.y, dz = qz - c.z;
                float d2 = fmaf(dx, dx, fmaf(dy, dy, dz * dz));
                best = fminf(best, d2);
            }
        }
    };

    scan_bucket(kstart);
    int down = kstart - 1, up = kstart + 1;
    while (true) {
        bool ndown = false, nup = false;
        if (down >= 0) {
            float dzd = fmaxf(qz - (zminY + (float)(down + 1) * wY), 0.f);
            ndown = dzd * dzd < best;                // conservative exact bound
        }
        if (up < NBUK) {
            float dzu = fmaxf((zminY + (float)up * wY) - qz, 0.f);
            nup = dzu * dzu < best;
        }
        const int cd = __syncthreads_count(ndown);
        const int cu = __syncthreads_count(nup);
        if (cd == 0 && cu == 0) break;
        if (cd) { scan_bucket(down); --down; }
        if (cu) { scan_bucket(up);   ++up;  }
    }

    // combine the two candidate-halves
    __shared__ float bh[128];
    __syncthreads();
    if (half) bh[t - 128] = best;
    __syncthreads();
    if (!half)
        bestd[((size_t)dir * NB + b) * NPTS + qi] = fminf(best, bh[t]);
}

// ---------- K6: sum 65536 mins (double), ticketed scalar write ----------
__global__ __launch_bounds__(256) void k_sum(
    const float* __restrict__ bestd, double* __restrict__ acc,
    unsigned int* __restrict__ counter, float* __restrict__ out) {
    const int g = blockIdx.x * 256 + threadIdx.x;
    const v4f v = ((const v4f*)bestd)[g];
    double d = (double)v.x + (double)v.y + (double)v.z + (double)v.w;
    for (int off = 32; off > 0; off >>= 1) d += __shfl_down(d, off);
    __shared__ double sh[4];
    const int lane = threadIdx.x & 63, w = threadIdx.x >> 6;
    if (lane == 0) sh[w] = d;
    __syncthreads();
    if (threadIdx.x == 0) {
        atomicAdd(acc, sh[0] + sh[1] + sh[2] + sh[3]);
        __threadfence();
        unsigned int tk = atomicAdd(counter, 1u);
        if (tk == gridDim.x - 1) {
            __threadfence();
            double s = atomicAdd(acc, 0.0);          // coherent final read
            out[0] = (float)(s / (double)(NB * NPTS));  // both dirs /32768
        }
    }
}

extern "C" void kernel_launch(void* const* d_in, const int* in_sizes, int n_in,
                              void* d_out, int out_size, void* d_ws, size_t ws_size,
                              hipStream_t stream) {
    const float* pred = (const float*)d_in[0];  // [B, N, 3]
    const float* targ = (const float*)d_in[1];  // [B, M, 3]
    float* out = (float*)d_out;

    v4f* scat = (v4f*)d_ws;                                   // 8*8192*16 = 1 MB
    double* acc = (double*)(scat + (size_t)NSETS * NPTS);     // 8B-aligned
    unsigned int* counter = (unsigned int*)(acc + 1);
    float* minmaxz = (float*)(counter + 3);
    int* counts = (int*)(minmaxz + 2 * NSETS);
    int* bukoff = counts + NSETS * NBUK;
    int* cursor = bukoff + NSETS * (NBUK + 1);
    float* bestd = (float*)(cursor + NSETS * NBUK);           // 65536 floats

    k_minmax<<<NSETS, 1024, 0, stream>>>(pred, targ, minmaxz, acc, counter);
    k_hist<<<NSETS, 1024, 0, stream>>>(pred, targ, minmaxz, counts);
    k_scan<<<1, 512, 0, stream>>>(counts, bukoff, cursor);
    k_scatter<<<NSETS, 1024, 0, stream>>>(pred, targ, minmaxz, cursor, scat);
    k_nn<<<dim3(NPTS / 128, NB, 2), 256, 0, stream>>>(scat, bukoff, minmaxz, bestd);
    k_sum<<<(2 * NB * NPTS / 4) / 256, 256, 0, stream>>>(bestd, acc, counter, out);
}